// Round 8
// baseline (563.710 us; speedup 1.0000x reference)
//
#include <hip/hip_runtime.h>

#define BN_EPS 1e-5f
#define SCAN_CHUNK 1024  // elements per scan block (256 thr x 4)
#define BM 128           // rows per MFMA-GEMM block (qkv)

typedef __attribute__((ext_vector_type(8))) short s16x8;
typedef __attribute__((ext_vector_type(8))) ushort u16x8;
typedef __attribute__((ext_vector_type(4))) float f32x4;

__device__ __forceinline__ ushort f2bf_rne(float f)
{
    unsigned u = __builtin_bit_cast(unsigned, f);
    return (ushort)((u + 0x7fffu + ((u >> 16) & 1u)) >> 16);
}

__device__ __forceinline__ float bf2f(ushort u)
{
    return __builtin_bit_cast(float, (unsigned)u << 16);
}

// ---------------------------------------------------------------- ea MLP + folded Q/K biases
__global__ __launch_bounds__(128) void k_ea(
    const float* __restrict__ nt, const float* __restrict__ et,
    const float* __restrict__ mW1, const float* __restrict__ mb1,
    const float* __restrict__ m_g, const float* __restrict__ m_b,
    const float* __restrict__ m_m, const float* __restrict__ m_v,
    const float* __restrict__ mW2, const float* __restrict__ mb2,
    const float* __restrict__ qW, const float* __restrict__ qb,
    const float* __restrict__ kW, const float* __restrict__ kb,
    float* __restrict__ eaq, float* __restrict__ eak)
{
    __shared__ float merged[256];
    __shared__ float h[128];
    __shared__ float sea[128];
    const int t = threadIdx.x;
    merged[t]       = nt[t];
    merged[128 + t] = et[t];
    __syncthreads();
    float acc = mb1[t];
    for (int i = 0; i < 256; ++i) acc = fmaf(merged[i], mW1[i * 128 + t], acc);
    acc = (acc - m_m[t]) * rsqrtf(m_v[t] + BN_EPS) * m_g[t] + m_b[t];
    h[t] = acc > 0.f ? acc : 0.f;
    __syncthreads();
    float acc2 = mb2[t];
    for (int k = 0; k < 128; ++k) acc2 = fmaf(h[k], mW2[k * 128 + t], acc2);
    sea[t] = acc2;
    __syncthreads();
    float aq = qb[t], ak = kb[t];
    for (int k = 0; k < 128; ++k) {
        const float e = sea[k];
        aq = fmaf(e, qW[k * 128 + t], aq);
        ak = fmaf(e, kW[k * 128 + t], ak);
    }
    eaq[t] = aq;
    eak[t] = ak;
}

// ---------------------------------------------------------------- bf16 hi/lo split helper
__device__ __forceinline__ void split_store(float w, ushort* __restrict__ base,
                                            int j, int k)
{
    unsigned u = __builtin_bit_cast(unsigned, w);
    unsigned hi = (u + 0x7fffu + ((u >> 16) & 1u)) >> 16;   // RNE to bf16
    float hif = __builtin_bit_cast(float, hi << 16);
    float res = w - hif;
    unsigned lo = __builtin_bit_cast(unsigned, res) >> 16;  // trunc of residual
    base[j * 128 + k]         = (ushort)hi;
    base[16384 + j * 128 + k] = (ushort)lo;
}

// ---------------------------------------------------------------- weight prep: W[k][j] -> transposed bf16 hi/lo planes
__global__ __launch_bounds__(128) void k_prep3(
    const float* __restrict__ W0, const float* __restrict__ W1,
    const float* __restrict__ W2, ushort* __restrict__ P)
{
    const int j = blockIdx.x;   // output column of W = row of Wt
    const int m = blockIdx.y;
    const int k = threadIdx.x;
    const float* W = (m == 0) ? W0 : (m == 1) ? W1 : W2;
    split_store(W[k * 128 + j], P + (size_t)m * 32768, j, k);
}

// out-chain prep: plane0 = Wa = resW@oW1 (fused residual path), plane1 = oW1, plane2 = oW2
__global__ __launch_bounds__(128) void k_prep_out(
    const float* __restrict__ resW, const float* __restrict__ oW1,
    const float* __restrict__ oW2, ushort* __restrict__ P)
{
    __shared__ float col[128];
    const int j = blockIdx.x;
    const int m = blockIdx.y;
    const int k = threadIdx.x;
    float w;
    if (m == 0) {
        col[k] = oW1[k * 128 + j];          // column j of oW1
        __syncthreads();
        float acc = 0.f;
        for (int i = 0; i < 128; ++i) acc = fmaf(resW[k * 128 + i], col[i], acc);
        w = acc;                             // Wa[k][j]
    } else {
        const float* W = (m == 1) ? oW1 : oW2;
        w = W[k * 128 + j];
    }
    split_store(w, P + (size_t)m * 32768, j, k);
}

// ---------------------------------------------------------------- LDS staging with XOR swizzle
// byte ^= (row&7)<<4  (breaks the 16-way conflict of the 256B row stride).
template <int NT>
__device__ __forceinline__ void stage_w(const ushort* __restrict__ wpl,
                                        ushort* __restrict__ sw, int tid)
{
    const uint4* src = (const uint4*)wpl;   // 4096 uint4 = hi plane then lo plane
#pragma unroll
    for (int it = 0; it < 4096 / NT; ++it) {
        const int idx = it * NT + tid;
        const uint4 v = src[idx];
        const int plane = idx >> 11;
        const int rr = (idx >> 4) & 127;
        const int cb = (idx & 15) << 4;                       // byte offset in row
        const int byteoff = ((rr * 256 + cb) ^ ((rr & 7) << 4));
        *(uint4*)((char*)sw + plane * 32768 + byteoff) = v;
    }
}

// single plane (32 KB)
template <int NT>
__device__ __forceinline__ void stage_w1(const ushort* __restrict__ wpl,
                                         ushort* __restrict__ sw, int tid)
{
    const uint4* src = (const uint4*)wpl;   // 2048 uint4
#pragma unroll
    for (int it = 0; it < 2048 / NT; ++it) {
        const int idx = it * NT + tid;
        const uint4 v = src[idx];
        const int rr = idx >> 4;
        const int cb = (idx & 15) << 4;
        const int byteoff = ((rr * 256 + cb) ^ ((rr & 7) << 4));
        *(uint4*)((char*)sw + byteoff) = v;
    }
}

// split a 128-float row into bf16 hi/lo fragments (k-slot convention shared with B reads)
__device__ __forceinline__ void split_row(const float* __restrict__ row, int g,
                                          s16x8* ah, s16x8* al)
{
#pragma unroll
    for (int ks = 0; ks < 4; ++ks) {
        const float* ap = row + ks * 32 + g * 8;
        const float4 a0 = *(const float4*)(ap);
        const float4 a1 = *(const float4*)(ap + 4);
        float av[8] = {a0.x, a0.y, a0.z, a0.w, a1.x, a1.y, a1.z, a1.w};
#pragma unroll
        for (int j = 0; j < 8; ++j) {
            const unsigned u = __builtin_bit_cast(unsigned, av[j]);
            ah[ks][j] = (short)(u >> 16);
            const float hif = __builtin_bit_cast(float, u & 0xffff0000u);
            const float res = av[j] - hif;
            al[ks][j] = (short)(__builtin_bit_cast(unsigned, res) >> 16);
        }
    }
}

// ---------------------------------------------------------------- MFMA cores
// bf16x3 from pre-split register A, 2-plane (hi+lo) staged B
template <int CT>
__device__ __forceinline__ void mm_reg3(const s16x8* ah, const s16x8* al,
                                        const ushort* __restrict__ sw,
                                        int g, int r16, int ct0, f32x4* acc)
{
#pragma unroll
    for (int ks = 0; ks < 4; ++ks) {
        const int koff = ks * 64 + g * 16;   // bytes within a Wt row
#pragma unroll
        for (int ct = 0; ct < CT; ++ct) {
            const int row = (ct0 + ct) * 16 + r16;
            const int byteoff = ((row * 256 + koff) ^ ((row & 7) << 4));
            const s16x8 bhi = *(const s16x8*)((const char*)sw + byteoff);
            const s16x8 blo = *(const s16x8*)((const char*)sw + 32768 + byteoff);
            acc[ct] = __builtin_amdgcn_mfma_f32_16x16x32_bf16(ah[ks], bhi, acc[ct], 0, 0, 0);
            acc[ct] = __builtin_amdgcn_mfma_f32_16x16x32_bf16(ah[ks], blo, acc[ct], 0, 0, 0);
            acc[ct] = __builtin_amdgcn_mfma_f32_16x16x32_bf16(al[ks], bhi, acc[ct], 0, 0, 0);
        }
    }
}

// single-plane passes (out3 path)
template <int CT>
__device__ __forceinline__ void mm_pass2(const s16x8* ah, const s16x8* al,
                                         const ushort* __restrict__ sw,
                                         int g, int r16, int ct0, f32x4* acc)
{
#pragma unroll
    for (int ks = 0; ks < 4; ++ks) {
        const int koff = ks * 64 + g * 16;
#pragma unroll
        for (int ct = 0; ct < CT; ++ct) {
            const int row = (ct0 + ct) * 16 + r16;
            const int byteoff = ((row * 256 + koff) ^ ((row & 7) << 4));
            const s16x8 b = *(const s16x8*)((const char*)sw + byteoff);
            acc[ct] = __builtin_amdgcn_mfma_f32_16x16x32_bf16(ah[ks], b, acc[ct], 0, 0, 0);
            acc[ct] = __builtin_amdgcn_mfma_f32_16x16x32_bf16(al[ks], b, acc[ct], 0, 0, 0);
        }
    }
}

template <int CT>
__device__ __forceinline__ void mm_pass1(const s16x8* a,
                                         const ushort* __restrict__ sw,
                                         int g, int r16, int ct0, f32x4* acc)
{
#pragma unroll
    for (int ks = 0; ks < 4; ++ks) {
        const int koff = ks * 64 + g * 16;
#pragma unroll
        for (int ct = 0; ct < CT; ++ct) {
            const int row = (ct0 + ct) * 16 + r16;
            const int byteoff = ((row * 256 + koff) ^ ((row & 7) << 4));
            const s16x8 b = *(const s16x8*)((const char*)sw + byteoff);
            acc[ct] = __builtin_amdgcn_mfma_f32_16x16x32_bf16(a[ks], b, acc[ct], 0, 0, 0);
        }
    }
}

// ---------------------------------------------------------------- fused Q/K/V via MFMA, single dispatch.
// x rows split to bf16 hi/lo registers ONCE; 3 weight stagings against held fragments.
// All outputs leave via LDS repack (full-line stores). 64 KB LDS -> 2 blocks/CU, 8 waves/SIMD.
__global__ __launch_bounds__(1024, 8) void k_mm_qkvF(
    const float* __restrict__ x, const ushort* __restrict__ planes,
    const float* __restrict__ eaq, const float* __restrict__ eak,
    const float* __restrict__ vb,
    float* __restrict__ Q, float* __restrict__ K, ushort* __restrict__ V16, int N)
{
    __shared__ ushort sw[2 * 128 * 128];   // 64 KB
    const int tid = threadIdx.x;
    const int wave = tid >> 6, lane = tid & 63;
    const int g = lane >> 4, r16 = lane & 15;
    const int wr = wave & 7, wc = wave >> 3;
    const int ct0 = wc * 4;
    const int n0 = blockIdx.x * BM;
    const int arow = wr * 16 + r16;
    int nA = n0 + arow; if (nA >= N) nA = N - 1;

    s16x8 ah[4], al[4];
    split_row(x + (size_t)nA * 128, g, ah, al);   // split ONCE for all 3 GEMMs

#pragma unroll
    for (int sel = 0; sel < 3; ++sel) {
        stage_w<1024>(planes + (size_t)sel * 32768, sw, tid);
        __syncthreads();

        f32x4 acc[4];
#pragma unroll
        for (int ct = 0; ct < 4; ++ct) acc[ct] = (f32x4){0.f, 0.f, 0.f, 0.f};
        mm_reg3<4>(ah, al, sw, g, r16, ct0, acc);
        __syncthreads();                   // all sw B-reads done; reuse as out buffer

        if (sel == 2) {
            ushort* vbuf = (ushort*)sw;    // [128][128] linear bf16
#pragma unroll
            for (int ct = 0; ct < 4; ++ct) {
                const int c = (ct0 + ct) * 16 + r16;
                const float bc = vb[c];
#pragma unroll
                for (int r = 0; r < 4; ++r) {
                    const int nrel = wr * 16 + g * 4 + r;   // D row = (lane>>4)*4 + reg  [m89]
                    vbuf[nrel * 128 + c] = f2bf_rne(acc[ct][r] + bc);
                }
            }
            __syncthreads();
            // coalesced copy-out: 1024 threads x 32 B
            const int row = tid >> 3;
            const int col = (tid & 7) * 16;
            if (n0 + row < N) {
                const uint4* src = (const uint4*)(vbuf + row * 128 + col);
                const uint4 v0 = src[0], v1 = src[1];
                uint4* dst = (uint4*)(V16 + (size_t)(n0 + row) * 128 + col);
                dst[0] = v0; dst[1] = v1;
            }
        } else {
            const float* bias = sel ? eak : eaq;
            float* O          = sel ? K   : Q;
            const float scale = sel ? 1.0f : 0.25f;   // q = (..)/sqrt(16)
            float* fbuf = (float*)sw;      // [128][128] f32, row-XOR swizzled
#pragma unroll
            for (int ct = 0; ct < 4; ++ct) {
                const int c = (ct0 + ct) * 16 + r16;
                const float bc = bias[c];
#pragma unroll
                for (int r = 0; r < 4; ++r) {
                    const int nrel = wr * 16 + g * 4 + r;
                    const int byteoff = (nrel * 512 + c * 4) ^ ((nrel & 7) << 4);
                    *(float*)((char*)fbuf + byteoff) = (acc[ct][r] + bc) * scale;
                }
            }
            __syncthreads();
            const float4* fb4 = (const float4*)fbuf;
#pragma unroll
            for (int it = 0; it < 4; ++it) {
                const int idx4 = it * 1024 + tid;    // 4096 float4
                const int row = idx4 >> 5;
                const int n = n0 + row;
                if (n < N)
                    *(float4*)(O + (size_t)n * 128 + (idx4 & 31) * 4) =
                        fb4[row * 32 + ((idx4 & 31) ^ (row & 7))];
            }
            __syncthreads();               // copy-out reads done before next stage
        }
    }
}

// ---------------------------------------------------------------- fused out chain, small-LDS (48 KB -> 3 blocks/CU):
// u = x@Wa + aggr@oW1; t = lrelu(bn(u+ob1)) -> LDS bf16; out = t@oW2 + ob2.
// Single-plane staging: per GEMM {hi-plane: Ahi*W + Alo*W} then {lo-plane: Ahi*W}.
// Only dropped term: t_lo @ oW2 (~4e-3 abs, negligible). out leaves via LDS repack.
__global__ __launch_bounds__(512, 4) void k_out3(
    const float* __restrict__ x, const ushort* __restrict__ Po,
    const float* __restrict__ aggr, const float* __restrict__ ob1,
    const float* __restrict__ o_m, const float* __restrict__ o_v,
    const float* __restrict__ o_g, const float* __restrict__ o_b,
    const float* __restrict__ ob2, float* __restrict__ out, int N)
{
    __shared__ ushort sw[128 * 128];   // 32 KB  (one weight plane / out tile)
    __shared__ ushort tb[64 * 128];    // 16 KB  (t tile, bf16 hi, swizzled)
    const int tid = threadIdx.x;
    const int wave = tid >> 6, lane = tid & 63;
    const int g = lane >> 4, r16 = lane & 15;
    const int wr = wave & 3, wc = wave >> 2;   // 4 row-groups x 2 col-halves
    const int ct0 = wc * 4;
    const int n0 = blockIdx.x * 64;
    const int arow = wr * 16 + r16;
    int nA = n0 + arow; if (nA >= N) nA = N - 1;

    s16x8 ah[4], al[4];
    split_row(x + (size_t)nA * 128, g, ah, al);

    f32x4 acc[4];
#pragma unroll
    for (int ct = 0; ct < 4; ++ct) acc[ct] = (f32x4){0.f, 0.f, 0.f, 0.f};

    // ---- GEMM1a: x @ Wa ----
    stage_w1<512>(Po, sw, tid); __syncthreads();
    mm_pass2<4>(ah, al, sw, g, r16, ct0, acc); __syncthreads();
    stage_w1<512>(Po + 16384, sw, tid); __syncthreads();
    mm_pass1<4>(ah, sw, g, r16, ct0, acc); __syncthreads();

    // ---- GEMM1b: += aggr @ oW1 ----
    split_row(aggr + (size_t)nA * 128, g, ah, al);
    stage_w1<512>(Po + 32768, sw, tid); __syncthreads();
    mm_pass2<4>(ah, al, sw, g, r16, ct0, acc); __syncthreads();
    stage_w1<512>(Po + 49152, sw, tid); __syncthreads();
    mm_pass1<4>(ah, sw, g, r16, ct0, acc); __syncthreads();

    // ---- epilogue: t = lrelu(bn(u+ob1)) -> tb (bf16, swizzled); stage W2_hi concurrently ----
#pragma unroll
    for (int ct = 0; ct < 4; ++ct) {
        const int c = (ct0 + ct) * 16 + r16;
        const float bc = ob1[c];
        const float rs = rsqrtf(o_v[c] + BN_EPS);
        const float mm = o_m[c], gg = o_g[c], bb = o_b[c];
#pragma unroll
        for (int r = 0; r < 4; ++r) {
            const int nrel = wr * 16 + g * 4 + r;
            float u = acc[ct][r] + bc;
            u = (u - mm) * rs * gg + bb;
            u = u > 0.f ? u : 0.01f * u;
            const int byteoff = ((nrel * 256 + c * 2) ^ ((nrel & 7) << 4));
            *(ushort*)((char*)tb + byteoff) = f2bf_rne(u);
        }
    }
    stage_w1<512>(Po + 65536, sw, tid);
    __syncthreads();

    // ---- GEMM3: out = t @ oW2 + ob2 (t_hi only) ----
    s16x8 ta[4];
#pragma unroll
    for (int ks = 0; ks < 4; ++ks) {
        const int byteoff = ((arow * 256 + ks * 64 + g * 16) ^ ((arow & 7) << 4));
        ta[ks] = *(const s16x8*)((const char*)tb + byteoff);
    }
#pragma unroll
    for (int ct = 0; ct < 4; ++ct) acc[ct] = (f32x4){0.f, 0.f, 0.f, 0.f};
    mm_pass1<4>(ta, sw, g, r16, ct0, acc);
    __syncthreads();
    stage_w1<512>(Po + 81920, sw, tid); __syncthreads();
    mm_pass1<4>(ta, sw, g, r16, ct0, acc);
    __syncthreads();                    // sw reads done; reuse as out buffer

    float* fbuf = (float*)sw;           // [64][128] f32, row-XOR swizzled (32 KB)
#pragma unroll
    for (int ct = 0; ct < 4; ++ct) {
        const int c = (ct0 + ct) * 16 + r16;
        const float bc = ob2[c];
#pragma unroll
        for (int r = 0; r < 4; ++r) {
            const int nrel = wr * 16 + g * 4 + r;
            const int byteoff = (nrel * 512 + c * 4) ^ ((nrel & 7) << 4);
            *(float*)((char*)fbuf + byteoff) = acc[ct][r] + bc;
        }
    }
    __syncthreads();
    const float4* fb4 = (const float4*)fbuf;
#pragma unroll
    for (int it = 0; it < 4; ++it) {
        const int idx4 = it * 512 + tid;     // 2048 float4
        const int row = idx4 >> 5;
        const int n = n0 + row;
        if (n < N)
            *(float4*)(out + (size_t)n * 128 + (idx4 & 31) * 4) =
                fb4[row * 32 + ((idx4 & 31) ^ (row & 7))];
    }
}

// ---------------------------------------------------------------- edge pass 1, CSR order: 1 wave / dst node,
// K[dst] resident in registers, 4 edges in flight (quarter-wave each).
__global__ __launch_bounds__(256) void k_edge1csr(
    const int* __restrict__ esrc, const int* __restrict__ row_start,
    const int* __restrict__ deg, const float* __restrict__ Q,
    const float* __restrict__ K, float* __restrict__ exp_,
    float* __restrict__ ssum, int N)
{
    const int tid = threadIdx.x;
    const int n = blockIdx.x * 4 + (tid >> 6);
    if (n >= N) return;
    const int lane = tid & 63;
    const int sub = lane >> 4;        // which edge of the quad
    const int l = lane & 15;
    const int h = l >> 1;             // head (2 lanes per head)
    const int c0 = l * 8;
    const int rs = row_start[n];
    const int dg = deg[n];
    // K[n] resident: 8 floats per lane (each quarter-wave holds the full row)
    const float4 k0 = *(const float4*)(K + (size_t)n * 128 + c0);
    const float4 k1 = *(const float4*)(K + (size_t)n * 128 + c0 + 4);
    for (int j = sub; j < dg; j += 4) {
        const int idx = rs + j;
        const int s = esrc[idx];                                  // 1-deep chain
        const float4 q0 = *(const float4*)(Q + (size_t)s * 128 + c0);
        const float4 q1 = *(const float4*)(Q + (size_t)s * 128 + c0 + 4);
        float p = q0.x * k0.x + q0.y * k0.y + q0.z * k0.z + q0.w * k0.w
                + q1.x * k1.x + q1.y * k1.y + q1.z * k1.z + q1.w * k1.w;
        p += __shfl_xor(p, 1, 64);    // reduce head pair
        if ((l & 1) == 0) {
            const float v = __expf(p);    // |score| small; no max-subtraction needed
            exp_[(size_t)idx * 8 + h] = v;            // streaming write
            unsafeAtomicAdd(&ssum[(size_t)s * 8 + h], v);
        }
    }
}

// ---------------------------------------------------------------- rsum = 1/ssum (in place)
__global__ __launch_bounds__(256) void k_rsum(float* __restrict__ ssum, int M)
{
    const int i = blockIdx.x * 256 + threadIdx.x;
    if (i < M) ssum[i] = 1.0f / ssum[i];
}

// ---------------------------------------------------------------- CSR build (dst)
__global__ __launch_bounds__(256) void k_hist(const int* __restrict__ ei,
                                              int* __restrict__ deg, int E)
{
    const int e = blockIdx.x * 256 + threadIdx.x;
    if (e < E) atomicAdd(&deg[ei[E + e]], 1);
}

__global__ __launch_bounds__(256) void k_scan_partial(const int* __restrict__ deg,
                                                      int* __restrict__ part, int N)
{
    __shared__ int sd[256];
    const int b = blockIdx.x, t = threadIdx.x;
    const int base = b * SCAN_CHUNK + t * 4;
    int s = 0;
#pragma unroll
    for (int i = 0; i < 4; ++i) { const int idx = base + i; if (idx < N) s += deg[idx]; }
    sd[t] = s; __syncthreads();
    for (int off = 128; off > 0; off >>= 1) {
        if (t < off) sd[t] += sd[t + off];
        __syncthreads();
    }
    if (t == 0) part[b] = sd[0];
}

__global__ __launch_bounds__(256) void k_scan_top(int* __restrict__ part, int nb)
{
    __shared__ int sd[256];
    const int t = threadIdx.x;
    const int orig = (t < nb) ? part[t] : 0;
    sd[t] = orig;
    __syncthreads();
    for (int off = 1; off < 256; off <<= 1) {
        const int v = (t >= off) ? sd[t - off] : 0;
        __syncthreads();
        sd[t] += v;
        __syncthreads();
    }
    if (t < nb) part[t] = sd[t] - orig;   // exclusive
}

__global__ __launch_bounds__(256) void k_scan_final(const int* __restrict__ deg,
                                                    const int* __restrict__ part,
                                                    int* __restrict__ row_start,
                                                    int* __restrict__ cursor, int N)
{
    __shared__ int ts[256];
    const int b = blockIdx.x, t = threadIdx.x;
    const int base = b * SCAN_CHUNK + t * 4;
    int v[4]; int s = 0;
#pragma unroll
    for (int i = 0; i < 4; ++i) { const int idx = base + i; v[i] = (idx < N) ? deg[idx] : 0; s += v[i]; }
    ts[t] = s; __syncthreads();
    for (int off = 1; off < 256; off <<= 1) {
        const int vv = (t >= off) ? ts[t - off] : 0;
        __syncthreads();
        ts[t] += vv;
        __syncthreads();
    }
    int run = part[b] + ((t > 0) ? ts[t - 1] : 0);
#pragma unroll
    for (int i = 0; i < 4; ++i) {
        const int idx = base + i;
        if (idx < N) { row_start[idx] = run; cursor[idx] = run; run += v[i]; }
    }
}

// scatter: record src node per CSR slot
__global__ __launch_bounds__(256) void k_scatter(const int* __restrict__ ei,
                                                 int* __restrict__ cursor,
                                                 int* __restrict__ esrc, int E)
{
    const int e = blockIdx.x * 256 + threadIdx.x;
    if (e < E) {
        const int pos = atomicAdd(&cursor[ei[E + e]], 1);
        esrc[pos] = ei[e];
    }
}

// ---------------------------------------------------------------- aggregation: 1 wave / dst node, 4 edges in flight
// V is bf16 (256 B/row gather, quarter-wave); alpha = exp * rsum[src,h] (rsum L2-resident).
__global__ __launch_bounds__(256) void k_aggr(
    const int* __restrict__ esrc, const int* __restrict__ row_start,
    const int* __restrict__ deg, const ushort* __restrict__ V16,
    const float* __restrict__ exp_, const float* __restrict__ rsum,
    float* __restrict__ aggr, int N)
{
    const int tid = threadIdx.x;
    const int n = blockIdx.x * 4 + (tid >> 6);
    if (n >= N) return;
    const int lane = tid & 63;
    const int sub = lane >> 4;        // which edge of the quad
    const int l = lane & 15;
    const int h = l >> 1;
    const int c0 = l * 8;
    const int rs = row_start[n];
    const int dg = deg[n];
    float a0 = 0.f, a1 = 0.f, a2 = 0.f, a3 = 0.f;
    float a4 = 0.f, a5 = 0.f, a6 = 0.f, a7 = 0.f;
    for (int j = sub; j < dg; j += 4) {
        const int idx = rs + j;
        const int s = esrc[idx];                           // 1-deep chain
        const float a = exp_[(size_t)idx * 8 + h] * rsum[(size_t)s * 8 + h];
        const u16x8 vu = *(const u16x8*)(V16 + (size_t)s * 128 + c0);
        a0 = fmaf(bf2f(vu[0]), a, a0);
        a1 = fmaf(bf2f(vu[1]), a, a1);
        a2 = fmaf(bf2f(vu[2]), a, a2);
        a3 = fmaf(bf2f(vu[3]), a, a3);
        a4 = fmaf(bf2f(vu[4]), a, a4);
        a5 = fmaf(bf2f(vu[5]), a, a5);
        a6 = fmaf(bf2f(vu[6]), a, a6);
        a7 = fmaf(bf2f(vu[7]), a, a7);
    }
    a0 += __shfl_xor(a0, 16, 64); a0 += __shfl_xor(a0, 32, 64);
    a1 += __shfl_xor(a1, 16, 64); a1 += __shfl_xor(a1, 32, 64);
    a2 += __shfl_xor(a2, 16, 64); a2 += __shfl_xor(a2, 32, 64);
    a3 += __shfl_xor(a3, 16, 64); a3 += __shfl_xor(a3, 32, 64);
    a4 += __shfl_xor(a4, 16, 64); a4 += __shfl_xor(a4, 32, 64);
    a5 += __shfl_xor(a5, 16, 64); a5 += __shfl_xor(a5, 32, 64);
    a6 += __shfl_xor(a6, 16, 64); a6 += __shfl_xor(a6, 32, 64);
    a7 += __shfl_xor(a7, 16, 64); a7 += __shfl_xor(a7, 32, 64);
    if (sub == 0) {
        float4 o0 = make_float4(a0, a1, a2, a3);
        float4 o1 = make_float4(a4, a5, a6, a7);
        *(float4*)(aggr + (size_t)n * 128 + c0)     = o0;
        *(float4*)(aggr + (size_t)n * 128 + c0 + 4) = o1;
    }
}

// ---------------------------------------------------------------- launch
extern "C" void kernel_launch(void* const* d_in, const int* in_sizes, int n_in,
                              void* d_out, int out_size, void* d_ws, size_t ws_size,
                              hipStream_t stream)
{
    const float* x    = (const float*)d_in[0];
    const int*   ei   = (const int*)d_in[1];
    const float* nt   = (const float*)d_in[2];
    const float* et   = (const float*)d_in[3];
    const float* mW1  = (const float*)d_in[4];
    const float* mb1  = (const float*)d_in[5];
    const float* m_g  = (const float*)d_in[6];
    const float* m_b  = (const float*)d_in[7];
    const float* m_m  = (const float*)d_in[8];
    const float* m_v  = (const float*)d_in[9];
    const float* mW2  = (const float*)d_in[10];
    const float* mb2  = (const float*)d_in[11];
    const float* resW = (const float*)d_in[12];
    const float* qW   = (const float*)d_in[13];
    const float* qb   = (const float*)d_in[14];
    const float* kW   = (const float*)d_in[15];
    const float* kb   = (const float*)d_in[16];
    const float* vW   = (const float*)d_in[17];
    const float* vb   = (const float*)d_in[18];
    const float* oW1  = (const float*)d_in[19];
    const float* ob1  = (const float*)d_in[20];
    const float* o_g  = (const float*)d_in[21];
    const float* o_b  = (const float*)d_in[22];
    const float* o_m  = (const float*)d_in[23];
    const float* o_v  = (const float*)d_in[24];
    const float* oW2  = (const float*)d_in[25];
    const float* ob2  = (const float*)d_in[26];
    float* out = (float*)d_out;

    const int N = in_sizes[0] / 128;
    const int E = in_sizes[1] / 2;

    // workspace layout (floats): eaq|eak | Q | K | V | exp | ssum | [ints] deg,row_start,cursor,part,esrc
    float* ws   = (float*)d_ws;
    float* eaq  = ws;
    float* eak  = ws + 128;
    float* Q    = ws + 256;
    float* K    = Q + (size_t)N * 128;
    float* V    = K + (size_t)N * 128;
    float* exp_ = V + (size_t)N * 128;
    float* ssum = exp_ + (size_t)E * 8;
    int* deg       = (int*)(ssum + (size_t)N * 8);
    int* row_start = deg + N;
    int* cursor    = row_start + N;
    int* part      = cursor + N;
    int* esrc      = part + 256;
    float* aggr = Q;              // Q dead after edge pass 1
    ushort* V16 = (ushort*)V;     // V in bf16 (half of V region)
    // bf16 weight planes live in dead regions:
    //   qkv planes in ssum (consumed by k_mm_qkvF BEFORE ssum memset)
    //   out planes in exp_ (written AFTER k_aggr, when exp_ is dead)
    ushort* Pq = (ushort*)ssum;   // 3 * 32768 ushorts = 192 KB  (<< N*8 floats)
    ushort* Po = (ushort*)exp_;   // 192 KB  (<< E*8 floats)

    const int nbm  = (N + BM - 1) / BM;
    const int nbo  = (N + 63) / 64;
    const int nbsc = (N + SCAN_CHUNK - 1) / SCAN_CHUNK;   // scan blocks (<=256)

    // --- weight prep + ea (before memsets; Pq aliases ssum) ---
    k_prep3<<<dim3(128, 3), 128, 0, stream>>>(qW, kW, vW, Pq);
    k_ea<<<1, 128, 0, stream>>>(nt, et, mW1, mb1, m_g, m_b, m_m, m_v, mW2, mb2,
                                qW, qb, kW, kb, eaq, eak);
    k_mm_qkvF<<<nbm, 1024, 0, stream>>>(x, Pq, eaq, eak, vb, Q, K, V16, N);

    // planes consumed -> now zero ssum/deg (stream-ordered)
    hipMemsetAsync(ssum, 0, (size_t)N * 8 * sizeof(float), stream);
    hipMemsetAsync(deg, 0, (size_t)N * sizeof(int), stream);

    // CSR build (independent of Q/K/V values)
    k_hist<<<(E + 255) / 256, 256, 0, stream>>>(ei, deg, E);
    k_scan_partial<<<nbsc, 256, 0, stream>>>(deg, part, N);
    k_scan_top<<<1, 256, 0, stream>>>(part, nbsc);
    k_scan_final<<<nbsc, 256, 0, stream>>>(deg, part, row_start, cursor, N);
    k_scatter<<<(E + 255) / 256, 256, 0, stream>>>(ei, cursor, esrc, E);

    // edge pass 1 in CSR order: K resident per node, streaming exp writes
    k_edge1csr<<<(N + 3) / 4, 256, 0, stream>>>(esrc, row_start, deg, Q, K, exp_, ssum, N);
    k_rsum<<<(N * 8 + 255) / 256, 256, 0, stream>>>(ssum, N * 8);
    k_aggr<<<(N + 3) / 4, 256, 0, stream>>>(esrc, row_start, deg, V16, exp_, ssum, aggr, N);

    // --- fused output chain via MFMA (exp_ dead now; Po aliases it) ---
    k_prep_out<<<dim3(128, 3), 128, 0, stream>>>(resW, oW1, oW2, Po);
    k_out3<<<nbo, 512, 0, stream>>>(x, Po, aggr, ob1, o_m, o_v, o_g, o_b, ob2, out, N);
}

// Round 9
// 437.944 us; speedup vs baseline: 1.2872x; 1.2872x over previous
//
#include <hip/hip_runtime.h>

#define BN_EPS 1e-5f
#define SCAN_CHUNK 1024  // elements per scan block (256 thr x 4)
#define BM 128           // rows per MFMA-GEMM block (qkv)

typedef __attribute__((ext_vector_type(8))) short s16x8;
typedef __attribute__((ext_vector_type(8))) ushort u16x8;
typedef __attribute__((ext_vector_type(4))) float f32x4;

__device__ __forceinline__ ushort f2bf_rne(float f)
{
    unsigned u = __builtin_bit_cast(unsigned, f);
    return (ushort)((u + 0x7fffu + ((u >> 16) & 1u)) >> 16);
}

__device__ __forceinline__ float bf2f(ushort u)
{
    return __builtin_bit_cast(float, (unsigned)u << 16);
}

// ---------------------------------------------------------------- ea MLP + folded Q/K biases
__global__ __launch_bounds__(128) void k_ea(
    const float* __restrict__ nt, const float* __restrict__ et,
    const float* __restrict__ mW1, const float* __restrict__ mb1,
    const float* __restrict__ m_g, const float* __restrict__ m_b,
    const float* __restrict__ m_m, const float* __restrict__ m_v,
    const float* __restrict__ mW2, const float* __restrict__ mb2,
    const float* __restrict__ qW, const float* __restrict__ qb,
    const float* __restrict__ kW, const float* __restrict__ kb,
    float* __restrict__ eaq, float* __restrict__ eak)
{
    __shared__ float merged[256];
    __shared__ float h[128];
    __shared__ float sea[128];
    const int t = threadIdx.x;
    merged[t]       = nt[t];
    merged[128 + t] = et[t];
    __syncthreads();
    float acc = mb1[t];
    for (int i = 0; i < 256; ++i) acc = fmaf(merged[i], mW1[i * 128 + t], acc);
    acc = (acc - m_m[t]) * rsqrtf(m_v[t] + BN_EPS) * m_g[t] + m_b[t];
    h[t] = acc > 0.f ? acc : 0.f;
    __syncthreads();
    float acc2 = mb2[t];
    for (int k = 0; k < 128; ++k) acc2 = fmaf(h[k], mW2[k * 128 + t], acc2);
    sea[t] = acc2;
    __syncthreads();
    float aq = qb[t], ak = kb[t];
    for (int k = 0; k < 128; ++k) {
        const float e = sea[k];
        aq = fmaf(e, qW[k * 128 + t], aq);
        ak = fmaf(e, kW[k * 128 + t], ak);
    }
    eaq[t] = aq;
    eak[t] = ak;
}

// ---------------------------------------------------------------- bf16 hi/lo split helper
__device__ __forceinline__ void split_store(float w, ushort* __restrict__ base,
                                            int j, int k)
{
    unsigned u = __builtin_bit_cast(unsigned, w);
    unsigned hi = (u + 0x7fffu + ((u >> 16) & 1u)) >> 16;   // RNE to bf16
    float hif = __builtin_bit_cast(float, hi << 16);
    float res = w - hif;
    unsigned lo = __builtin_bit_cast(unsigned, res) >> 16;  // trunc of residual
    base[j * 128 + k]         = (ushort)hi;
    base[16384 + j * 128 + k] = (ushort)lo;
}

// ---------------------------------------------------------------- weight prep: W[k][j] -> transposed bf16 hi/lo planes
__global__ __launch_bounds__(128) void k_prep3(
    const float* __restrict__ W0, const float* __restrict__ W1,
    const float* __restrict__ W2, ushort* __restrict__ P)
{
    const int j = blockIdx.x;   // output column of W = row of Wt
    const int m = blockIdx.y;
    const int k = threadIdx.x;
    const float* W = (m == 0) ? W0 : (m == 1) ? W1 : W2;
    split_store(W[k * 128 + j], P + (size_t)m * 32768, j, k);
}

// out-chain prep: plane0 = Wa = resW@oW1 (fused residual path), plane1 = oW1, plane2 = oW2
__global__ __launch_bounds__(128) void k_prep_out(
    const float* __restrict__ resW, const float* __restrict__ oW1,
    const float* __restrict__ oW2, ushort* __restrict__ P)
{
    __shared__ float col[128];
    const int j = blockIdx.x;
    const int m = blockIdx.y;
    const int k = threadIdx.x;
    float w;
    if (m == 0) {
        col[k] = oW1[k * 128 + j];          // column j of oW1
        __syncthreads();
        float acc = 0.f;
        for (int i = 0; i < 128; ++i) acc = fmaf(resW[k * 128 + i], col[i], acc);
        w = acc;                             // Wa[k][j]
    } else {
        const float* W = (m == 1) ? oW1 : oW2;
        w = W[k * 128 + j];
    }
    split_store(w, P + (size_t)m * 32768, j, k);
}

// ---------------------------------------------------------------- LDS staging with XOR swizzle
// byte ^= (row&7)<<4  (breaks the 16-way conflict of the 256B row stride).
template <int NT>
__device__ __forceinline__ void stage_w(const ushort* __restrict__ wpl,
                                        ushort* __restrict__ sw, int tid)
{
    const uint4* src = (const uint4*)wpl;   // 4096 uint4 = hi plane then lo plane
#pragma unroll
    for (int it = 0; it < 4096 / NT; ++it) {
        const int idx = it * NT + tid;
        const uint4 v = src[idx];
        const int plane = idx >> 11;
        const int rr = (idx >> 4) & 127;
        const int cb = (idx & 15) << 4;                       // byte offset in row
        const int byteoff = ((rr * 256 + cb) ^ ((rr & 7) << 4));
        *(uint4*)((char*)sw + plane * 32768 + byteoff) = v;
    }
}

// single plane (32 KB)
template <int NT>
__device__ __forceinline__ void stage_w1(const ushort* __restrict__ wpl,
                                         ushort* __restrict__ sw, int tid)
{
    const uint4* src = (const uint4*)wpl;   // 2048 uint4
#pragma unroll
    for (int it = 0; it < 2048 / NT; ++it) {
        const int idx = it * NT + tid;
        const uint4 v = src[idx];
        const int rr = idx >> 4;
        const int cb = (idx & 15) << 4;
        const int byteoff = ((rr * 256 + cb) ^ ((rr & 7) << 4));
        *(uint4*)((char*)sw + byteoff) = v;
    }
}

// split a 128-float row into bf16 hi/lo fragments (k-slot convention shared with B reads)
__device__ __forceinline__ void split_row(const float* __restrict__ row, int g,
                                          s16x8* ah, s16x8* al)
{
#pragma unroll
    for (int ks = 0; ks < 4; ++ks) {
        const float* ap = row + ks * 32 + g * 8;
        const float4 a0 = *(const float4*)(ap);
        const float4 a1 = *(const float4*)(ap + 4);
        float av[8] = {a0.x, a0.y, a0.z, a0.w, a1.x, a1.y, a1.z, a1.w};
#pragma unroll
        for (int j = 0; j < 8; ++j) {
            const unsigned u = __builtin_bit_cast(unsigned, av[j]);
            ah[ks][j] = (short)(u >> 16);
            const float hif = __builtin_bit_cast(float, u & 0xffff0000u);
            const float res = av[j] - hif;
            al[ks][j] = (short)(__builtin_bit_cast(unsigned, res) >> 16);
        }
    }
}

// ---------------------------------------------------------------- MFMA cores
// 2-plane (hi+lo B) bf16x3 from f32 A  (qkv path; split inside loop -> low VGPR, no spill)
template <int CT>
__device__ __forceinline__ void mm_core(const float* __restrict__ Arow,
                                        const ushort* __restrict__ sw,
                                        int g, int r16, int ct0, f32x4* acc)
{
#pragma unroll
    for (int ks = 0; ks < 4; ++ks) {
        const float* ap = Arow + ks * 32 + g * 8;
        const float4 a0 = *(const float4*)(ap);
        const float4 a1 = *(const float4*)(ap + 4);
        float av[8] = {a0.x, a0.y, a0.z, a0.w, a1.x, a1.y, a1.z, a1.w};
        s16x8 ahi, alo;
#pragma unroll
        for (int j = 0; j < 8; ++j) {
            const unsigned u = __builtin_bit_cast(unsigned, av[j]);
            ahi[j] = (short)(u >> 16);
            const float hif = __builtin_bit_cast(float, u & 0xffff0000u);
            const float res = av[j] - hif;
            alo[j] = (short)(__builtin_bit_cast(unsigned, res) >> 16);
        }
        const int koff = ks * 64 + g * 16;   // bytes within a Wt row
#pragma unroll
        for (int ct = 0; ct < CT; ++ct) {
            const int row = (ct0 + ct) * 16 + r16;
            const int byteoff = ((row * 256 + koff) ^ ((row & 7) << 4));
            const s16x8 bhi = *(const s16x8*)((const char*)sw + byteoff);
            const s16x8 blo = *(const s16x8*)((const char*)sw + 32768 + byteoff);
            acc[ct] = __builtin_amdgcn_mfma_f32_16x16x32_bf16(ahi, bhi, acc[ct], 0, 0, 0);
            acc[ct] = __builtin_amdgcn_mfma_f32_16x16x32_bf16(ahi, blo, acc[ct], 0, 0, 0);
            acc[ct] = __builtin_amdgcn_mfma_f32_16x16x32_bf16(alo, bhi, acc[ct], 0, 0, 0);
        }
    }
}

// single-plane passes (out3 path)
template <int CT>
__device__ __forceinline__ void mm_pass2(const s16x8* ah, const s16x8* al,
                                         const ushort* __restrict__ sw,
                                         int g, int r16, int ct0, f32x4* acc)
{
#pragma unroll
    for (int ks = 0; ks < 4; ++ks) {
        const int koff = ks * 64 + g * 16;
#pragma unroll
        for (int ct = 0; ct < CT; ++ct) {
            const int row = (ct0 + ct) * 16 + r16;
            const int byteoff = ((row * 256 + koff) ^ ((row & 7) << 4));
            const s16x8 b = *(const s16x8*)((const char*)sw + byteoff);
            acc[ct] = __builtin_amdgcn_mfma_f32_16x16x32_bf16(ah[ks], b, acc[ct], 0, 0, 0);
            acc[ct] = __builtin_amdgcn_mfma_f32_16x16x32_bf16(al[ks], b, acc[ct], 0, 0, 0);
        }
    }
}

template <int CT>
__device__ __forceinline__ void mm_pass1(const s16x8* a,
                                         const ushort* __restrict__ sw,
                                         int g, int r16, int ct0, f32x4* acc)
{
#pragma unroll
    for (int ks = 0; ks < 4; ++ks) {
        const int koff = ks * 64 + g * 16;
#pragma unroll
        for (int ct = 0; ct < CT; ++ct) {
            const int row = (ct0 + ct) * 16 + r16;
            const int byteoff = ((row * 256 + koff) ^ ((row & 7) << 4));
            const s16x8 b = *(const s16x8*)((const char*)sw + byteoff);
            acc[ct] = __builtin_amdgcn_mfma_f32_16x16x32_bf16(a[ks], b, acc[ct], 0, 0, 0);
        }
    }
}

// ---------------------------------------------------------------- Q/K/V via MFMA, 1024 thr, 2 blocks/CU
// blockIdx.y selects matrix. Q and V written bf16 via LDS repack; K f32 via LDS repack.
// (round-7 structure: per-block split inside mm_core keeps VGPRs low -> no scratch spill)
__global__ __launch_bounds__(1024, 8) void k_mm_qkv(
    const float* __restrict__ x, const ushort* __restrict__ planes,
    const float* __restrict__ eaq, const float* __restrict__ eak,
    const float* __restrict__ vb,
    ushort* __restrict__ Q16, float* __restrict__ K, ushort* __restrict__ V16, int N)
{
    __shared__ ushort sw[2 * 128 * 128];   // 64 KB
    const int tid = threadIdx.x;
    const int sel = blockIdx.y;
    stage_w<1024>(planes + (size_t)sel * 32768, sw, tid);
    __syncthreads();

    const int wave = tid >> 6, lane = tid & 63;
    const int g = lane >> 4, r16 = lane & 15;
    const int wr = wave & 7, wc = wave >> 3;
    const int ct0 = wc * 4;
    const int n0 = blockIdx.x * BM;
    const int arow = wr * 16 + r16;
    int nA = n0 + arow; if (nA >= N) nA = N - 1;

    f32x4 acc[4];
#pragma unroll
    for (int ct = 0; ct < 4; ++ct) acc[ct] = (f32x4){0.f, 0.f, 0.f, 0.f};
    mm_core<4>(x + (size_t)nA * 128, sw, g, r16, ct0, acc);
    __syncthreads();                       // all sw B-reads done; reuse as out buffer

    if (sel != 1) {
        // bf16 outputs: Q16 (sel 0, scaled) or V16 (sel 2)
        ushort* vbuf = (ushort*)sw;        // [128][128] linear bf16
        const float* bias  = sel ? vb  : eaq;
        ushort* Obf        = sel ? V16 : Q16;
        const float scale  = sel ? 1.0f : 0.25f;   // q = (..)/sqrt(16)
#pragma unroll
        for (int ct = 0; ct < 4; ++ct) {
            const int c = (ct0 + ct) * 16 + r16;
            const float bc = bias[c];
#pragma unroll
            for (int r = 0; r < 4; ++r) {
                const int nrel = wr * 16 + g * 4 + r;   // D row = (lane>>4)*4 + reg  [m89]
                vbuf[nrel * 128 + c] = f2bf_rne((acc[ct][r] + bc) * scale);
            }
        }
        __syncthreads();
        // coalesced copy-out: 1024 threads x 32 B
        const int row = tid >> 3;
        const int col = (tid & 7) * 16;
        if (n0 + row < N) {
            const uint4* src = (const uint4*)(vbuf + row * 128 + col);
            const uint4 v0 = src[0], v1 = src[1];
            uint4* dst = (uint4*)(Obf + (size_t)(n0 + row) * 128 + col);
            dst[0] = v0; dst[1] = v1;
        }
    } else {
        float* fbuf = (float*)sw;          // [128][128] f32, row-XOR swizzled
#pragma unroll
        for (int ct = 0; ct < 4; ++ct) {
            const int c = (ct0 + ct) * 16 + r16;
            const float bc = eak[c];
#pragma unroll
            for (int r = 0; r < 4; ++r) {
                const int nrel = wr * 16 + g * 4 + r;
                const int byteoff = (nrel * 512 + c * 4) ^ ((nrel & 7) << 4);
                *(float*)((char*)fbuf + byteoff) = acc[ct][r] + bc;
            }
        }
        __syncthreads();
        const float4* fb4 = (const float4*)fbuf;
#pragma unroll
        for (int it = 0; it < 4; ++it) {
            const int idx4 = it * 1024 + tid;    // 4096 float4
            const int row = idx4 >> 5;
            const int n = n0 + row;
            if (n < N)
                *(float4*)(K + (size_t)n * 128 + (idx4 & 31) * 4) =
                    fb4[row * 32 + ((idx4 & 31) ^ (row & 7))];
        }
    }
}

// ---------------------------------------------------------------- fused out chain, small-LDS (48 KB -> 3 blocks/CU):
// u = x@Wa + aggr@oW1; t = lrelu(bn(u+ob1)) -> LDS bf16; out = t@oW2 + ob2.
// Single-plane staging: per GEMM {hi-plane: Ahi*W + Alo*W} then {lo-plane: Ahi*W}.
// Only dropped term: t_lo @ oW2 (~4e-3 abs, negligible). out leaves via LDS repack.
__global__ __launch_bounds__(512, 4) void k_out3(
    const float* __restrict__ x, const ushort* __restrict__ Po,
    const float* __restrict__ aggr, const float* __restrict__ ob1,
    const float* __restrict__ o_m, const float* __restrict__ o_v,
    const float* __restrict__ o_g, const float* __restrict__ o_b,
    const float* __restrict__ ob2, float* __restrict__ out, int N)
{
    __shared__ ushort sw[128 * 128];   // 32 KB  (one weight plane / out tile)
    __shared__ ushort tb[64 * 128];    // 16 KB  (t tile, bf16 hi, swizzled)
    const int tid = threadIdx.x;
    const int wave = tid >> 6, lane = tid & 63;
    const int g = lane >> 4, r16 = lane & 15;
    const int wr = wave & 3, wc = wave >> 2;   // 4 row-groups x 2 col-halves
    const int ct0 = wc * 4;
    const int n0 = blockIdx.x * 64;
    const int arow = wr * 16 + r16;
    int nA = n0 + arow; if (nA >= N) nA = N - 1;

    s16x8 ah[4], al[4];
    split_row(x + (size_t)nA * 128, g, ah, al);

    f32x4 acc[4];
#pragma unroll
    for (int ct = 0; ct < 4; ++ct) acc[ct] = (f32x4){0.f, 0.f, 0.f, 0.f};

    // ---- GEMM1a: x @ Wa ----
    stage_w1<512>(Po, sw, tid); __syncthreads();
    mm_pass2<4>(ah, al, sw, g, r16, ct0, acc); __syncthreads();
    stage_w1<512>(Po + 16384, sw, tid); __syncthreads();
    mm_pass1<4>(ah, sw, g, r16, ct0, acc); __syncthreads();

    // ---- GEMM1b: += aggr @ oW1 ----
    split_row(aggr + (size_t)nA * 128, g, ah, al);
    stage_w1<512>(Po + 32768, sw, tid); __syncthreads();
    mm_pass2<4>(ah, al, sw, g, r16, ct0, acc); __syncthreads();
    stage_w1<512>(Po + 49152, sw, tid); __syncthreads();
    mm_pass1<4>(ah, sw, g, r16, ct0, acc); __syncthreads();

    // ---- epilogue: t = lrelu(bn(u+ob1)) -> tb (bf16, swizzled); stage W2_hi concurrently ----
#pragma unroll
    for (int ct = 0; ct < 4; ++ct) {
        const int c = (ct0 + ct) * 16 + r16;
        const float bc = ob1[c];
        const float rs = rsqrtf(o_v[c] + BN_EPS);
        const float mm = o_m[c], gg = o_g[c], bb = o_b[c];
#pragma unroll
        for (int r = 0; r < 4; ++r) {
            const int nrel = wr * 16 + g * 4 + r;
            float u = acc[ct][r] + bc;
            u = (u - mm) * rs * gg + bb;
            u = u > 0.f ? u : 0.01f * u;
            const int byteoff = ((nrel * 256 + c * 2) ^ ((nrel & 7) << 4));
            *(ushort*)((char*)tb + byteoff) = f2bf_rne(u);
        }
    }
    stage_w1<512>(Po + 65536, sw, tid);
    __syncthreads();

    // ---- GEMM3: out = t @ oW2 + ob2 (t_hi only) ----
    s16x8 ta[4];
#pragma unroll
    for (int ks = 0; ks < 4; ++ks) {
        const int byteoff = ((arow * 256 + ks * 64 + g * 16) ^ ((arow & 7) << 4));
        ta[ks] = *(const s16x8*)((const char*)tb + byteoff);
    }
#pragma unroll
    for (int ct = 0; ct < 4; ++ct) acc[ct] = (f32x4){0.f, 0.f, 0.f, 0.f};
    mm_pass1<4>(ta, sw, g, r16, ct0, acc);
    __syncthreads();
    stage_w1<512>(Po + 81920, sw, tid); __syncthreads();
    mm_pass1<4>(ta, sw, g, r16, ct0, acc);
    __syncthreads();                    // sw reads done; reuse as out buffer

    float* fbuf = (float*)sw;           // [64][128] f32, row-XOR swizzled (32 KB)
#pragma unroll
    for (int ct = 0; ct < 4; ++ct) {
        const int c = (ct0 + ct) * 16 + r16;
        const float bc = ob2[c];
#pragma unroll
        for (int r = 0; r < 4; ++r) {
            const int nrel = wr * 16 + g * 4 + r;
            const int byteoff = (nrel * 512 + c * 4) ^ ((nrel & 7) << 4);
            *(float*)((char*)fbuf + byteoff) = acc[ct][r] + bc;
        }
    }
    __syncthreads();
    const float4* fb4 = (const float4*)fbuf;
#pragma unroll
    for (int it = 0; it < 4; ++it) {
        const int idx4 = it * 512 + tid;     // 2048 float4
        const int row = idx4 >> 5;
        const int n = n0 + row;
        if (n < N)
            *(float4*)(out + (size_t)n * 128 + (idx4 & 31) * 4) =
                fb4[row * 32 + ((idx4 & 31) ^ (row & 7))];
    }
}

// ---------------------------------------------------------------- edge pass 1, CSR order: 1 wave / dst node,
// K[dst] resident in registers (f32), Q gathered as bf16 (256 B/edge, half the traffic).
// 4 edges in flight (quarter-wave each).
__global__ __launch_bounds__(256) void k_edge1csr(
    const int* __restrict__ esrc, const int* __restrict__ row_start,
    const int* __restrict__ deg, const ushort* __restrict__ Q16,
    const float* __restrict__ K, float* __restrict__ exp_,
    float* __restrict__ ssum, int N)
{
    const int tid = threadIdx.x;
    const int n = blockIdx.x * 4 + (tid >> 6);
    if (n >= N) return;
    const int lane = tid & 63;
    const int sub = lane >> 4;        // which edge of the quad
    const int l = lane & 15;
    const int h = l >> 1;             // head (2 lanes per head)
    const int c0 = l * 8;
    const int rs = row_start[n];
    const int dg = deg[n];
    // K[n] resident: 8 floats per lane (each quarter-wave holds the full row)
    const float4 k0 = *(const float4*)(K + (size_t)n * 128 + c0);
    const float4 k1 = *(const float4*)(K + (size_t)n * 128 + c0 + 4);
    for (int j = sub; j < dg; j += 4) {
        const int idx = rs + j;
        const int s = esrc[idx];                                  // 1-deep chain
        const u16x8 qv = *(const u16x8*)(Q16 + (size_t)s * 128 + c0);
        float p = bf2f(qv[0]) * k0.x + bf2f(qv[1]) * k0.y
                + bf2f(qv[2]) * k0.z + bf2f(qv[3]) * k0.w
                + bf2f(qv[4]) * k1.x + bf2f(qv[5]) * k1.y
                + bf2f(qv[6]) * k1.z + bf2f(qv[7]) * k1.w;
        p += __shfl_xor(p, 1, 64);    // reduce head pair
        if ((l & 1) == 0) {
            const float v = __expf(p);    // |score| small; no max-subtraction needed
            exp_[(size_t)idx * 8 + h] = v;            // streaming write
            unsafeAtomicAdd(&ssum[(size_t)s * 8 + h], v);
        }
    }
}

// ---------------------------------------------------------------- rsum = 1/ssum (in place)
__global__ __launch_bounds__(256) void k_rsum(float* __restrict__ ssum, int M)
{
    const int i = blockIdx.x * 256 + threadIdx.x;
    if (i < M) ssum[i] = 1.0f / ssum[i];
}

// ---------------------------------------------------------------- CSR build (dst)
__global__ __launch_bounds__(256) void k_hist(const int* __restrict__ ei,
                                              int* __restrict__ deg, int E)
{
    const int e = blockIdx.x * 256 + threadIdx.x;
    if (e < E) atomicAdd(&deg[ei[E + e]], 1);
}

__global__ __launch_bounds__(256) void k_scan_partial(const int* __restrict__ deg,
                                                      int* __restrict__ part, int N)
{
    __shared__ int sd[256];
    const int b = blockIdx.x, t = threadIdx.x;
    const int base = b * SCAN_CHUNK + t * 4;
    int s = 0;
#pragma unroll
    for (int i = 0; i < 4; ++i) { const int idx = base + i; if (idx < N) s += deg[idx]; }
    sd[t] = s; __syncthreads();
    for (int off = 128; off > 0; off >>= 1) {
        if (t < off) sd[t] += sd[t + off];
        __syncthreads();
    }
    if (t == 0) part[b] = sd[0];
}

__global__ __launch_bounds__(256) void k_scan_top(int* __restrict__ part, int nb)
{
    __shared__ int sd[256];
    const int t = threadIdx.x;
    const int orig = (t < nb) ? part[t] : 0;
    sd[t] = orig;
    __syncthreads();
    for (int off = 1; off < 256; off <<= 1) {
        const int v = (t >= off) ? sd[t - off] : 0;
        __syncthreads();
        sd[t] += v;
        __syncthreads();
    }
    if (t < nb) part[t] = sd[t] - orig;   // exclusive
}

__global__ __launch_bounds__(256) void k_scan_final(const int* __restrict__ deg,
                                                    const int* __restrict__ part,
                                                    int* __restrict__ row_start,
                                                    int* __restrict__ cursor, int N)
{
    __shared__ int ts[256];
    const int b = blockIdx.x, t = threadIdx.x;
    const int base = b * SCAN_CHUNK + t * 4;
    int v[4]; int s = 0;
#pragma unroll
    for (int i = 0; i < 4; ++i) { const int idx = base + i; v[i] = (idx < N) ? deg[idx] : 0; s += v[i]; }
    ts[t] = s; __syncthreads();
    for (int off = 1; off < 256; off <<= 1) {
        const int vv = (t >= off) ? ts[t - off] : 0;
        __syncthreads();
        ts[t] += vv;
        __syncthreads();
    }
    int run = part[b] + ((t > 0) ? ts[t - 1] : 0);
#pragma unroll
    for (int i = 0; i < 4; ++i) {
        const int idx = base + i;
        if (idx < N) { row_start[idx] = run; cursor[idx] = run; run += v[i]; }
    }
}

// scatter: record src node per CSR slot
__global__ __launch_bounds__(256) void k_scatter(const int* __restrict__ ei,
                                                 int* __restrict__ cursor,
                                                 int* __restrict__ esrc, int E)
{
    const int e = blockIdx.x * 256 + threadIdx.x;
    if (e < E) {
        const int pos = atomicAdd(&cursor[ei[E + e]], 1);
        esrc[pos] = ei[e];
    }
}

// ---------------------------------------------------------------- aggregation: 1 wave / dst node, 4 edges in flight
// V is bf16 (256 B/row gather, quarter-wave); alpha = exp * rsum[src,h] (rsum L2-resident).
__global__ __launch_bounds__(256) void k_aggr(
    const int* __restrict__ esrc, const int* __restrict__ row_start,
    const int* __restrict__ deg, const ushort* __restrict__ V16,
    const float* __restrict__ exp_, const float* __restrict__ rsum,
    float* __restrict__ aggr, int N)
{
    const int tid = threadIdx.x;
    const int n = blockIdx.x * 4 + (tid >> 6);
    if (n >= N) return;
    const int lane = tid & 63;
    const int sub = lane >> 4;        // which edge of the quad
    const int l = lane & 15;
    const int h = l >> 1;
    const int c0 = l * 8;
    const int rs = row_start[n];
    const int dg = deg[n];
    float a0 = 0.f, a1 = 0.f, a2 = 0.f, a3 = 0.f;
    float a4 = 0.f, a5 = 0.f, a6 = 0.f, a7 = 0.f;
    for (int j = sub; j < dg; j += 4) {
        const int idx = rs + j;
        const int s = esrc[idx];                           // 1-deep chain
        const float a = exp_[(size_t)idx * 8 + h] * rsum[(size_t)s * 8 + h];
        const u16x8 vu = *(const u16x8*)(V16 + (size_t)s * 128 + c0);
        a0 = fmaf(bf2f(vu[0]), a, a0);
        a1 = fmaf(bf2f(vu[1]), a, a1);
        a2 = fmaf(bf2f(vu[2]), a, a2);
        a3 = fmaf(bf2f(vu[3]), a, a3);
        a4 = fmaf(bf2f(vu[4]), a, a4);
        a5 = fmaf(bf2f(vu[5]), a, a5);
        a6 = fmaf(bf2f(vu[6]), a, a6);
        a7 = fmaf(bf2f(vu[7]), a, a7);
    }
    a0 += __shfl_xor(a0, 16, 64); a0 += __shfl_xor(a0, 32, 64);
    a1 += __shfl_xor(a1, 16, 64); a1 += __shfl_xor(a1, 32, 64);
    a2 += __shfl_xor(a2, 16, 64); a2 += __shfl_xor(a2, 32, 64);
    a3 += __shfl_xor(a3, 16, 64); a3 += __shfl_xor(a3, 32, 64);
    a4 += __shfl_xor(a4, 16, 64); a4 += __shfl_xor(a4, 32, 64);
    a5 += __shfl_xor(a5, 16, 64); a5 += __shfl_xor(a5, 32, 64);
    a6 += __shfl_xor(a6, 16, 64); a6 += __shfl_xor(a6, 32, 64);
    a7 += __shfl_xor(a7, 16, 64); a7 += __shfl_xor(a7, 32, 64);
    if (sub == 0) {
        float4 o0 = make_float4(a0, a1, a2, a3);
        float4 o1 = make_float4(a4, a5, a6, a7);
        *(float4*)(aggr + (size_t)n * 128 + c0)     = o0;
        *(float4*)(aggr + (size_t)n * 128 + c0 + 4) = o1;
    }
}

// ---------------------------------------------------------------- launch
extern "C" void kernel_launch(void* const* d_in, const int* in_sizes, int n_in,
                              void* d_out, int out_size, void* d_ws, size_t ws_size,
                              hipStream_t stream)
{
    const float* x    = (const float*)d_in[0];
    const int*   ei   = (const int*)d_in[1];
    const float* nt   = (const float*)d_in[2];
    const float* et   = (const float*)d_in[3];
    const float* mW1  = (const float*)d_in[4];
    const float* mb1  = (const float*)d_in[5];
    const float* m_g  = (const float*)d_in[6];
    const float* m_b  = (const float*)d_in[7];
    const float* m_m  = (const float*)d_in[8];
    const float* m_v  = (const float*)d_in[9];
    const float* mW2  = (const float*)d_in[10];
    const float* mb2  = (const float*)d_in[11];
    const float* resW = (const float*)d_in[12];
    const float* qW   = (const float*)d_in[13];
    const float* qb   = (const float*)d_in[14];
    const float* kW   = (const float*)d_in[15];
    const float* kb   = (const float*)d_in[16];
    const float* vW   = (const float*)d_in[17];
    const float* vb   = (const float*)d_in[18];
    const float* oW1  = (const float*)d_in[19];
    const float* ob1  = (const float*)d_in[20];
    const float* o_g  = (const float*)d_in[21];
    const float* o_b  = (const float*)d_in[22];
    const float* o_m  = (const float*)d_in[23];
    const float* o_v  = (const float*)d_in[24];
    const float* oW2  = (const float*)d_in[25];
    const float* ob2  = (const float*)d_in[26];
    float* out = (float*)d_out;

    const int N = in_sizes[0] / 128;
    const int E = in_sizes[1] / 2;

    // workspace layout (floats): eaq|eak | Q | K | V | exp | ssum | [ints] deg,row_start,cursor,part,esrc
    float* ws   = (float*)d_ws;
    float* eaq  = ws;
    float* eak  = ws + 128;
    float* Q    = ws + 256;
    float* K    = Q + (size_t)N * 128;
    float* V    = K + (size_t)N * 128;
    float* exp_ = V + (size_t)N * 128;
    float* ssum = exp_ + (size_t)E * 8;
    int* deg       = (int*)(ssum + (size_t)N * 8);
    int* row_start = deg + N;
    int* cursor    = row_start + N;
    int* part      = cursor + N;
    int* esrc      = part + 256;
    float* aggr = Q;              // Q dead after edge pass 1 (Q16 uses half the region)
    ushort* Q16 = (ushort*)Q;     // Q in bf16
    ushort* V16 = (ushort*)V;     // V in bf16
    // bf16 weight planes live in dead regions:
    //   qkv planes in ssum (consumed by k_mm_qkv BEFORE ssum memset)
    //   out planes in exp_ (written AFTER k_aggr, when exp_ is dead)
    ushort* Pq = (ushort*)ssum;   // 3 * 32768 ushorts = 192 KB  (<< N*8 floats)
    ushort* Po = (ushort*)exp_;   // 192 KB  (<< E*8 floats)

    const int nbm  = (N + BM - 1) / BM;
    const int nbo  = (N + 63) / 64;
    const int nbsc = (N + SCAN_CHUNK - 1) / SCAN_CHUNK;   // scan blocks (<=256)

    // --- weight prep + ea (before memsets; Pq aliases ssum) ---
    k_prep3<<<dim3(128, 3), 128, 0, stream>>>(qW, kW, vW, Pq);
    k_ea<<<1, 128, 0, stream>>>(nt, et, mW1, mb1, m_g, m_b, m_m, m_v, mW2, mb2,
                                qW, qb, kW, kb, eaq, eak);
    k_mm_qkv<<<dim3(nbm, 3), 1024, 0, stream>>>(x, Pq, eaq, eak, vb, Q16, K, V16, N);

    // planes consumed -> now zero ssum/deg (stream-ordered)
    hipMemsetAsync(ssum, 0, (size_t)N * 8 * sizeof(float), stream);
    hipMemsetAsync(deg, 0, (size_t)N * sizeof(int), stream);

    // CSR build (independent of Q/K/V values)
    k_hist<<<(E + 255) / 256, 256, 0, stream>>>(ei, deg, E);
    k_scan_partial<<<nbsc, 256, 0, stream>>>(deg, part, N);
    k_scan_top<<<1, 256, 0, stream>>>(part, nbsc);
    k_scan_final<<<nbsc, 256, 0, stream>>>(deg, part, row_start, cursor, N);
    k_scatter<<<(E + 255) / 256, 256, 0, stream>>>(ei, cursor, esrc, E);

    // edge pass 1 in CSR order: K resident per node, bf16 Q gather, streaming exp writes
    k_edge1csr<<<(N + 3) / 4, 256, 0, stream>>>(esrc, row_start, deg, Q16, K, exp_, ssum, N);
    k_rsum<<<(N * 8 + 255) / 256, 256, 0, stream>>>(ssum, N * 8);
    k_aggr<<<(N + 3) / 4, 256, 0, stream>>>(esrc, row_start, deg, V16, exp_, ssum, aggr, N);

    // --- fused output chain via MFMA (exp_ dead now; Po aliases it) ---
    k_prep_out<<<dim3(128, 3), 128, 0, stream>>>(resW, oW1, oW2, Po);
    k_out3<<<nbo, 512, 0, stream>>>(x, Po, aggr, ob1, o_m, o_v, o_g, o_b, ob2, out, N);
}

// Round 10
// 435.335 us; speedup vs baseline: 1.2949x; 1.0060x over previous
//
#include <hip/hip_runtime.h>

#define BN_EPS 1e-5f
#define SCAN_CHUNK 1024  // elements per scan block (256 thr x 4)
#define BM 128           // rows per MFMA-GEMM block (qkv)

typedef __attribute__((ext_vector_type(8))) short s16x8;
typedef __attribute__((ext_vector_type(8))) ushort u16x8;
typedef __attribute__((ext_vector_type(4))) float f32x4;

__device__ __forceinline__ ushort f2bf_rne(float f)
{
    unsigned u = __builtin_bit_cast(unsigned, f);
    return (ushort)((u + 0x7fffu + ((u >> 16) & 1u)) >> 16);
}

__device__ __forceinline__ float bf2f(ushort u)
{
    return __builtin_bit_cast(float, (unsigned)u << 16);
}

// ---------------------------------------------------------------- ea MLP + folded Q/K biases
__global__ __launch_bounds__(128) void k_ea(
    const float* __restrict__ nt, const float* __restrict__ et,
    const float* __restrict__ mW1, const float* __restrict__ mb1,
    const float* __restrict__ m_g, const float* __restrict__ m_b,
    const float* __restrict__ m_m, const float* __restrict__ m_v,
    const float* __restrict__ mW2, const float* __restrict__ mb2,
    const float* __restrict__ qW, const float* __restrict__ qb,
    const float* __restrict__ kW, const float* __restrict__ kb,
    float* __restrict__ eaq, float* __restrict__ eak)
{
    __shared__ float merged[256];
    __shared__ float h[128];
    __shared__ float sea[128];
    const int t = threadIdx.x;
    merged[t]       = nt[t];
    merged[128 + t] = et[t];
    __syncthreads();
    float acc = mb1[t];
    for (int i = 0; i < 256; ++i) acc = fmaf(merged[i], mW1[i * 128 + t], acc);
    acc = (acc - m_m[t]) * rsqrtf(m_v[t] + BN_EPS) * m_g[t] + m_b[t];
    h[t] = acc > 0.f ? acc : 0.f;
    __syncthreads();
    float acc2 = mb2[t];
    for (int k = 0; k < 128; ++k) acc2 = fmaf(h[k], mW2[k * 128 + t], acc2);
    sea[t] = acc2;
    __syncthreads();
    float aq = qb[t], ak = kb[t];
    for (int k = 0; k < 128; ++k) {
        const float e = sea[k];
        aq = fmaf(e, qW[k * 128 + t], aq);
        ak = fmaf(e, kW[k * 128 + t], ak);
    }
    eaq[t] = aq;
    eak[t] = ak;
}

// ---------------------------------------------------------------- bf16 hi/lo split helper
__device__ __forceinline__ void split_store(float w, ushort* __restrict__ base,
                                            int j, int k)
{
    unsigned u = __builtin_bit_cast(unsigned, w);
    unsigned hi = (u + 0x7fffu + ((u >> 16) & 1u)) >> 16;   // RNE to bf16
    float hif = __builtin_bit_cast(float, hi << 16);
    float res = w - hif;
    unsigned lo = __builtin_bit_cast(unsigned, res) >> 16;  // trunc of residual
    base[j * 128 + k]         = (ushort)hi;
    base[16384 + j * 128 + k] = (ushort)lo;
}

// ---------------------------------------------------------------- weight prep: W[k][j] -> transposed bf16 hi/lo planes
__global__ __launch_bounds__(128) void k_prep3(
    const float* __restrict__ W0, const float* __restrict__ W1,
    const float* __restrict__ W2, ushort* __restrict__ P)
{
    const int j = blockIdx.x;   // output column of W = row of Wt
    const int m = blockIdx.y;
    const int k = threadIdx.x;
    const float* W = (m == 0) ? W0 : (m == 1) ? W1 : W2;
    split_store(W[k * 128 + j], P + (size_t)m * 32768, j, k);
}

// out-chain prep: plane0 = Wa = resW@oW1 (fused residual path), plane1 = oW1, plane2 = oW2
__global__ __launch_bounds__(128) void k_prep_out(
    const float* __restrict__ resW, const float* __restrict__ oW1,
    const float* __restrict__ oW2, ushort* __restrict__ P)
{
    __shared__ float col[128];
    const int j = blockIdx.x;
    const int m = blockIdx.y;
    const int k = threadIdx.x;
    float w;
    if (m == 0) {
        col[k] = oW1[k * 128 + j];          // column j of oW1
        __syncthreads();
        float acc = 0.f;
        for (int i = 0; i < 128; ++i) acc = fmaf(resW[k * 128 + i], col[i], acc);
        w = acc;                             // Wa[k][j]
    } else {
        const float* W = (m == 1) ? oW1 : oW2;
        w = W[k * 128 + j];
    }
    split_store(w, P + (size_t)m * 32768, j, k);
}

// ---------------------------------------------------------------- LDS staging with XOR swizzle
// byte ^= (row&7)<<4  (breaks the 16-way conflict of the 256B row stride).
template <int NT>
__device__ __forceinline__ void stage_w(const ushort* __restrict__ wpl,
                                        ushort* __restrict__ sw, int tid)
{
    const uint4* src = (const uint4*)wpl;   // 4096 uint4 = hi plane then lo plane
#pragma unroll
    for (int it = 0; it < 4096 / NT; ++it) {
        const int idx = it * NT + tid;
        const uint4 v = src[idx];
        const int plane = idx >> 11;
        const int rr = (idx >> 4) & 127;
        const int cb = (idx & 15) << 4;                       // byte offset in row
        const int byteoff = ((rr * 256 + cb) ^ ((rr & 7) << 4));
        *(uint4*)((char*)sw + plane * 32768 + byteoff) = v;
    }
}

// single plane (32 KB)
template <int NT>
__device__ __forceinline__ void stage_w1(const ushort* __restrict__ wpl,
                                         ushort* __restrict__ sw, int tid)
{
    const uint4* src = (const uint4*)wpl;   // 2048 uint4
#pragma unroll
    for (int it = 0; it < 2048 / NT; ++it) {
        const int idx = it * NT + tid;
        const uint4 v = src[idx];
        const int rr = idx >> 4;
        const int cb = (idx & 15) << 4;
        const int byteoff = ((rr * 256 + cb) ^ ((rr & 7) << 4));
        *(uint4*)((char*)sw + byteoff) = v;
    }
}

// split a 128-float row into bf16 hi/lo fragments (k-slot convention shared with B reads)
__device__ __forceinline__ void split_row(const float* __restrict__ row, int g,
                                          s16x8* ah, s16x8* al)
{
#pragma unroll
    for (int ks = 0; ks < 4; ++ks) {
        const float* ap = row + ks * 32 + g * 8;
        const float4 a0 = *(const float4*)(ap);
        const float4 a1 = *(const float4*)(ap + 4);
        float av[8] = {a0.x, a0.y, a0.z, a0.w, a1.x, a1.y, a1.z, a1.w};
#pragma unroll
        for (int j = 0; j < 8; ++j) {
            const unsigned u = __builtin_bit_cast(unsigned, av[j]);
            ah[ks][j] = (short)(u >> 16);
            const float hif = __builtin_bit_cast(float, u & 0xffff0000u);
            const float res = av[j] - hif;
            al[ks][j] = (short)(__builtin_bit_cast(unsigned, res) >> 16);
        }
    }
}

// ---------------------------------------------------------------- MFMA cores
// 2-plane (hi+lo B) bf16x3 from f32 A  (qkv path; split inside loop -> low VGPR, no spill)
template <int CT>
__device__ __forceinline__ void mm_core(const float* __restrict__ Arow,
                                        const ushort* __restrict__ sw,
                                        int g, int r16, int ct0, f32x4* acc)
{
#pragma unroll
    for (int ks = 0; ks < 4; ++ks) {
        const float* ap = Arow + ks * 32 + g * 8;
        const float4 a0 = *(const float4*)(ap);
        const float4 a1 = *(const float4*)(ap + 4);
        float av[8] = {a0.x, a0.y, a0.z, a0.w, a1.x, a1.y, a1.z, a1.w};
        s16x8 ahi, alo;
#pragma unroll
        for (int j = 0; j < 8; ++j) {
            const unsigned u = __builtin_bit_cast(unsigned, av[j]);
            ahi[j] = (short)(u >> 16);
            const float hif = __builtin_bit_cast(float, u & 0xffff0000u);
            const float res = av[j] - hif;
            alo[j] = (short)(__builtin_bit_cast(unsigned, res) >> 16);
        }
        const int koff = ks * 64 + g * 16;   // bytes within a Wt row
#pragma unroll
        for (int ct = 0; ct < CT; ++ct) {
            const int row = (ct0 + ct) * 16 + r16;
            const int byteoff = ((row * 256 + koff) ^ ((row & 7) << 4));
            const s16x8 bhi = *(const s16x8*)((const char*)sw + byteoff);
            const s16x8 blo = *(const s16x8*)((const char*)sw + 32768 + byteoff);
            acc[ct] = __builtin_amdgcn_mfma_f32_16x16x32_bf16(ahi, bhi, acc[ct], 0, 0, 0);
            acc[ct] = __builtin_amdgcn_mfma_f32_16x16x32_bf16(ahi, blo, acc[ct], 0, 0, 0);
            acc[ct] = __builtin_amdgcn_mfma_f32_16x16x32_bf16(alo, bhi, acc[ct], 0, 0, 0);
        }
    }
}

// single-plane passes (out4 path)
template <int CT>
__device__ __forceinline__ void mm_pass2(const s16x8* ah, const s16x8* al,
                                         const ushort* __restrict__ sw,
                                         int g, int r16, int ct0, f32x4* acc)
{
#pragma unroll
    for (int ks = 0; ks < 4; ++ks) {
        const int koff = ks * 64 + g * 16;
#pragma unroll
        for (int ct = 0; ct < CT; ++ct) {
            const int row = (ct0 + ct) * 16 + r16;
            const int byteoff = ((row * 256 + koff) ^ ((row & 7) << 4));
            const s16x8 b = *(const s16x8*)((const char*)sw + byteoff);
            acc[ct] = __builtin_amdgcn_mfma_f32_16x16x32_bf16(ah[ks], b, acc[ct], 0, 0, 0);
            acc[ct] = __builtin_amdgcn_mfma_f32_16x16x32_bf16(al[ks], b, acc[ct], 0, 0, 0);
        }
    }
}

template <int CT>
__device__ __forceinline__ void mm_pass1(const s16x8* a,
                                         const ushort* __restrict__ sw,
                                         int g, int r16, int ct0, f32x4* acc)
{
#pragma unroll
    for (int ks = 0; ks < 4; ++ks) {
        const int koff = ks * 64 + g * 16;
#pragma unroll
        for (int ct = 0; ct < CT; ++ct) {
            const int row = (ct0 + ct) * 16 + r16;
            const int byteoff = ((row * 256 + koff) ^ ((row & 7) << 4));
            const s16x8 b = *(const s16x8*)((const char*)sw + byteoff);
            acc[ct] = __builtin_amdgcn_mfma_f32_16x16x32_bf16(a[ks], b, acc[ct], 0, 0, 0);
        }
    }
}

// ---------------------------------------------------------------- Q/K/V via MFMA, 1024 thr, 2 blocks/CU
// blockIdx.y selects matrix. Q and V written bf16 via LDS repack; K f32 via LDS repack.
__global__ __launch_bounds__(1024, 8) void k_mm_qkv(
    const float* __restrict__ x, const ushort* __restrict__ planes,
    const float* __restrict__ eaq, const float* __restrict__ eak,
    const float* __restrict__ vb,
    ushort* __restrict__ Q16, float* __restrict__ K, ushort* __restrict__ V16, int N)
{
    __shared__ ushort sw[2 * 128 * 128];   // 64 KB
    const int tid = threadIdx.x;
    const int sel = blockIdx.y;
    stage_w<1024>(planes + (size_t)sel * 32768, sw, tid);
    __syncthreads();

    const int wave = tid >> 6, lane = tid & 63;
    const int g = lane >> 4, r16 = lane & 15;
    const int wr = wave & 7, wc = wave >> 3;
    const int ct0 = wc * 4;
    const int n0 = blockIdx.x * BM;
    const int arow = wr * 16 + r16;
    int nA = n0 + arow; if (nA >= N) nA = N - 1;

    f32x4 acc[4];
#pragma unroll
    for (int ct = 0; ct < 4; ++ct) acc[ct] = (f32x4){0.f, 0.f, 0.f, 0.f};
    mm_core<4>(x + (size_t)nA * 128, sw, g, r16, ct0, acc);
    __syncthreads();                       // all sw B-reads done; reuse as out buffer

    if (sel != 1) {
        // bf16 outputs: Q16 (sel 0, scaled) or V16 (sel 2)
        ushort* vbuf = (ushort*)sw;        // [128][128] linear bf16
        const float* bias  = sel ? vb  : eaq;
        ushort* Obf        = sel ? V16 : Q16;
        const float scale  = sel ? 1.0f : 0.25f;   // q = (..)/sqrt(16)
#pragma unroll
        for (int ct = 0; ct < 4; ++ct) {
            const int c = (ct0 + ct) * 16 + r16;
            const float bc = bias[c];
#pragma unroll
            for (int r = 0; r < 4; ++r) {
                const int nrel = wr * 16 + g * 4 + r;   // D row = (lane>>4)*4 + reg  [m89]
                vbuf[nrel * 128 + c] = f2bf_rne((acc[ct][r] + bc) * scale);
            }
        }
        __syncthreads();
        // coalesced copy-out: 1024 threads x 32 B
        const int row = tid >> 3;
        const int col = (tid & 7) * 16;
        if (n0 + row < N) {
            const uint4* src = (const uint4*)(vbuf + row * 128 + col);
            const uint4 v0 = src[0], v1 = src[1];
            uint4* dst = (uint4*)(Obf + (size_t)(n0 + row) * 128 + col);
            dst[0] = v0; dst[1] = v1;
        }
    } else {
        float* fbuf = (float*)sw;          // [128][128] f32, row-XOR swizzled
#pragma unroll
        for (int ct = 0; ct < 4; ++ct) {
            const int c = (ct0 + ct) * 16 + r16;
            const float bc = eak[c];
#pragma unroll
            for (int r = 0; r < 4; ++r) {
                const int nrel = wr * 16 + g * 4 + r;
                const int byteoff = (nrel * 512 + c * 4) ^ ((nrel & 7) << 4);
                *(float*)((char*)fbuf + byteoff) = acc[ct][r] + bc;
            }
        }
        __syncthreads();
        const float4* fb4 = (const float4*)fbuf;
#pragma unroll
        for (int it = 0; it < 4; ++it) {
            const int idx4 = it * 1024 + tid;    // 4096 float4
            const int row = idx4 >> 5;
            const int n = n0 + row;
            if (n < N)
                *(float4*)(K + (size_t)n * 128 + (idx4 & 31) * 4) =
                    fb4[row * 32 + ((idx4 & 31) ^ (row & 7))];
        }
    }
}

// ---------------------------------------------------------------- fused out chain v4: BM=128, CT=8, 512 thr.
// Each wave owns 16 rows x ALL 128 cols -> 2x MFMA per barrier, half the stagings
// per output row vs BM=64. LDS: one 64 KB arena (sw 32K | tb 32K; full arena reused
// as f32 out tile at the end). 2 blocks/CU at __launch_bounds__(512,4) (VGPR cap 128).
__global__ __launch_bounds__(512, 4) void k_out4(
    const float* __restrict__ x, const ushort* __restrict__ Po,
    const float* __restrict__ aggr, const float* __restrict__ ob1,
    const float* __restrict__ o_m, const float* __restrict__ o_v,
    const float* __restrict__ o_g, const float* __restrict__ o_b,
    const float* __restrict__ ob2, float* __restrict__ out, int N)
{
    __shared__ ushort lds[2 * 128 * 128];   // 64 KB arena
    ushort* sw = lds;                        // 32 KB: weight plane
    ushort* tb = lds + 16384;                // 32 KB: t tile (bf16 hi, swizzled)
    const int tid = threadIdx.x;
    const int wave = tid >> 6, lane = tid & 63;
    const int g = lane >> 4, r16 = lane & 15;
    const int wr = wave;                     // 8 row-groups, full col range
    const int n0 = blockIdx.x * 128;
    const int arow = wr * 16 + r16;
    int nA = n0 + arow; if (nA >= N) nA = N - 1;

    s16x8 ah[4], al[4];
    split_row(x + (size_t)nA * 128, g, ah, al);

    f32x4 acc[8];
#pragma unroll
    for (int ct = 0; ct < 8; ++ct) acc[ct] = (f32x4){0.f, 0.f, 0.f, 0.f};

    // ---- GEMM1a: x @ Wa ----
    stage_w1<512>(Po, sw, tid); __syncthreads();
    mm_pass2<8>(ah, al, sw, g, r16, 0, acc); __syncthreads();
    stage_w1<512>(Po + 16384, sw, tid); __syncthreads();
    mm_pass1<8>(ah, sw, g, r16, 0, acc); __syncthreads();

    // ---- GEMM1b: += aggr @ oW1 ----
    split_row(aggr + (size_t)nA * 128, g, ah, al);
    stage_w1<512>(Po + 32768, sw, tid); __syncthreads();
    mm_pass2<8>(ah, al, sw, g, r16, 0, acc); __syncthreads();
    stage_w1<512>(Po + 49152, sw, tid); __syncthreads();
    mm_pass1<8>(ah, sw, g, r16, 0, acc); __syncthreads();

    // ---- epilogue: t = lrelu(bn(u+ob1)) -> tb (bf16, swizzled); stage W2_hi concurrently ----
#pragma unroll
    for (int ct = 0; ct < 8; ++ct) {
        const int c = ct * 16 + r16;
        const float bc = ob1[c];
        const float rs = rsqrtf(o_v[c] + BN_EPS);
        const float mm = o_m[c], gg = o_g[c], bb = o_b[c];
#pragma unroll
        for (int r = 0; r < 4; ++r) {
            const int nrel = wr * 16 + g * 4 + r;
            float u = acc[ct][r] + bc;
            u = (u - mm) * rs * gg + bb;
            u = u > 0.f ? u : 0.01f * u;
            const int byteoff = ((nrel * 256 + c * 2) ^ ((nrel & 7) << 4));
            *(ushort*)((char*)tb + byteoff) = f2bf_rne(u);
        }
    }
    stage_w1<512>(Po + 65536, sw, tid);
    __syncthreads();

    // ---- GEMM3: out = t @ oW2 + ob2 (t_hi only) ----
    s16x8 ta[4];
#pragma unroll
    for (int ks = 0; ks < 4; ++ks) {
        const int byteoff = ((arow * 256 + ks * 64 + g * 16) ^ ((arow & 7) << 4));
        ta[ks] = *(const s16x8*)((const char*)tb + byteoff);
    }
#pragma unroll
    for (int ct = 0; ct < 8; ++ct) acc[ct] = (f32x4){0.f, 0.f, 0.f, 0.f};
    mm_pass1<8>(ta, sw, g, r16, 0, acc);
    __syncthreads();
    stage_w1<512>(Po + 81920, sw, tid); __syncthreads();
    mm_pass1<8>(ta, sw, g, r16, 0, acc);
    __syncthreads();                    // sw + tb reads done; reuse whole arena

    float* fbuf = (float*)lds;          // [128][128] f32, row-XOR swizzled (64 KB)
#pragma unroll
    for (int ct = 0; ct < 8; ++ct) {
        const int c = ct * 16 + r16;
        const float bc = ob2[c];
#pragma unroll
        for (int r = 0; r < 4; ++r) {
            const int nrel = wr * 16 + g * 4 + r;
            const int byteoff = (nrel * 512 + c * 4) ^ ((nrel & 7) << 4);
            *(float*)((char*)fbuf + byteoff) = acc[ct][r] + bc;
        }
    }
    __syncthreads();
    const float4* fb4 = (const float4*)fbuf;
#pragma unroll
    for (int it = 0; it < 8; ++it) {
        const int idx4 = it * 512 + tid;     // 4096 float4
        const int row = idx4 >> 5;
        const int n = n0 + row;
        if (n < N)
            *(float4*)(out + (size_t)n * 128 + (idx4 & 31) * 4) =
                fb4[row * 32 + ((idx4 & 31) ^ (row & 7))];
    }
}

// ---------------------------------------------------------------- edge pass 1, CSR order: 1 wave / dst node,
// K[dst] resident in registers (f32), Q gathered as bf16 (256 B/edge, half the traffic).
// 4 edges in flight (quarter-wave each).
__global__ __launch_bounds__(256) void k_edge1csr(
    const int* __restrict__ esrc, const int* __restrict__ row_start,
    const int* __restrict__ deg, const ushort* __restrict__ Q16,
    const float* __restrict__ K, float* __restrict__ exp_,
    float* __restrict__ ssum, int N)
{
    const int tid = threadIdx.x;
    const int n = blockIdx.x * 4 + (tid >> 6);
    if (n >= N) return;
    const int lane = tid & 63;
    const int sub = lane >> 4;        // which edge of the quad
    const int l = lane & 15;
    const int h = l >> 1;             // head (2 lanes per head)
    const int c0 = l * 8;
    const int rs = row_start[n];
    const int dg = deg[n];
    // K[n] resident: 8 floats per lane (each quarter-wave holds the full row)
    const float4 k0 = *(const float4*)(K + (size_t)n * 128 + c0);
    const float4 k1 = *(const float4*)(K + (size_t)n * 128 + c0 + 4);
    for (int j = sub; j < dg; j += 4) {
        const int idx = rs + j;
        const int s = esrc[idx];                                  // 1-deep chain
        const u16x8 qv = *(const u16x8*)(Q16 + (size_t)s * 128 + c0);
        float p = bf2f(qv[0]) * k0.x + bf2f(qv[1]) * k0.y
                + bf2f(qv[2]) * k0.z + bf2f(qv[3]) * k0.w
                + bf2f(qv[4]) * k1.x + bf2f(qv[5]) * k1.y
                + bf2f(qv[6]) * k1.z + bf2f(qv[7]) * k1.w;
        p += __shfl_xor(p, 1, 64);    // reduce head pair
        if ((l & 1) == 0) {
            const float v = __expf(p);    // |score| small; no max-subtraction needed
            exp_[(size_t)idx * 8 + h] = v;            // streaming write
            unsafeAtomicAdd(&ssum[(size_t)s * 8 + h], v);
        }
    }
}

// ---------------------------------------------------------------- rsum = 1/ssum (in place)
__global__ __launch_bounds__(256) void k_rsum(float* __restrict__ ssum, int M)
{
    const int i = blockIdx.x * 256 + threadIdx.x;
    if (i < M) ssum[i] = 1.0f / ssum[i];
}

// ---------------------------------------------------------------- CSR build (dst)
__global__ __launch_bounds__(256) void k_hist(const int* __restrict__ ei,
                                              int* __restrict__ deg, int E)
{
    const int e = blockIdx.x * 256 + threadIdx.x;
    if (e < E) atomicAdd(&deg[ei[E + e]], 1);
}

__global__ __launch_bounds__(256) void k_scan_partial(const int* __restrict__ deg,
                                                      int* __restrict__ part, int N)
{
    __shared__ int sd[256];
    const int b = blockIdx.x, t = threadIdx.x;
    const int base = b * SCAN_CHUNK + t * 4;
    int s = 0;
#pragma unroll
    for (int i = 0; i < 4; ++i) { const int idx = base + i; if (idx < N) s += deg[idx]; }
    sd[t] = s; __syncthreads();
    for (int off = 128; off > 0; off >>= 1) {
        if (t < off) sd[t] += sd[t + off];
        __syncthreads();
    }
    if (t == 0) part[b] = sd[0];
}

__global__ __launch_bounds__(256) void k_scan_top(int* __restrict__ part, int nb)
{
    __shared__ int sd[256];
    const int t = threadIdx.x;
    const int orig = (t < nb) ? part[t] : 0;
    sd[t] = orig;
    __syncthreads();
    for (int off = 1; off < 256; off <<= 1) {
        const int v = (t >= off) ? sd[t - off] : 0;
        __syncthreads();
        sd[t] += v;
        __syncthreads();
    }
    if (t < nb) part[t] = sd[t] - orig;   // exclusive
}

__global__ __launch_bounds__(256) void k_scan_final(const int* __restrict__ deg,
                                                    const int* __restrict__ part,
                                                    int* __restrict__ row_start,
                                                    int* __restrict__ cursor, int N)
{
    __shared__ int ts[256];
    const int b = blockIdx.x, t = threadIdx.x;
    const int base = b * SCAN_CHUNK + t * 4;
    int v[4]; int s = 0;
#pragma unroll
    for (int i = 0; i < 4; ++i) { const int idx = base + i; v[i] = (idx < N) ? deg[idx] : 0; s += v[i]; }
    ts[t] = s; __syncthreads();
    for (int off = 1; off < 256; off <<= 1) {
        const int vv = (t >= off) ? ts[t - off] : 0;
        __syncthreads();
        ts[t] += vv;
        __syncthreads();
    }
    int run = part[b] + ((t > 0) ? ts[t - 1] : 0);
#pragma unroll
    for (int i = 0; i < 4; ++i) {
        const int idx = base + i;
        if (idx < N) { row_start[idx] = run; cursor[idx] = run; run += v[i]; }
    }
}

// scatter: record src node per CSR slot
__global__ __launch_bounds__(256) void k_scatter(const int* __restrict__ ei,
                                                 int* __restrict__ cursor,
                                                 int* __restrict__ esrc, int E)
{
    const int e = blockIdx.x * 256 + threadIdx.x;
    if (e < E) {
        const int pos = atomicAdd(&cursor[ei[E + e]], 1);
        esrc[pos] = ei[e];
    }
}

// ---------------------------------------------------------------- aggregation: 1 wave / dst node, 4 edges in flight
// V is bf16 (256 B/row gather, quarter-wave); alpha = exp * rsum[src,h] (rsum L2-resident).
__global__ __launch_bounds__(256) void k_aggr(
    const int* __restrict__ esrc, const int* __restrict__ row_start,
    const int* __restrict__ deg, const ushort* __restrict__ V16,
    const float* __restrict__ exp_, const float* __restrict__ rsum,
    float* __restrict__ aggr, int N)
{
    const int tid = threadIdx.x;
    const int n = blockIdx.x * 4 + (tid >> 6);
    if (n >= N) return;
    const int lane = tid & 63;
    const int sub = lane >> 4;        // which edge of the quad
    const int l = lane & 15;
    const int h = l >> 1;
    const int c0 = l * 8;
    const int rs = row_start[n];
    const int dg = deg[n];
    float a0 = 0.f, a1 = 0.f, a2 = 0.f, a3 = 0.f;
    float a4 = 0.f, a5 = 0.f, a6 = 0.f, a7 = 0.f;
    for (int j = sub; j < dg; j += 4) {
        const int idx = rs + j;
        const int s = esrc[idx];                           // 1-deep chain
        const float a = exp_[(size_t)idx * 8 + h] * rsum[(size_t)s * 8 + h];
        const u16x8 vu = *(const u16x8*)(V16 + (size_t)s * 128 + c0);
        a0 = fmaf(bf2f(vu[0]), a, a0);
        a1 = fmaf(bf2f(vu[1]), a, a1);
        a2 = fmaf(bf2f(vu[2]), a, a2);
        a3 = fmaf(bf2f(vu[3]), a, a3);
        a4 = fmaf(bf2f(vu[4]), a, a4);
        a5 = fmaf(bf2f(vu[5]), a, a5);
        a6 = fmaf(bf2f(vu[6]), a, a6);
        a7 = fmaf(bf2f(vu[7]), a, a7);
    }
    a0 += __shfl_xor(a0, 16, 64); a0 += __shfl_xor(a0, 32, 64);
    a1 += __shfl_xor(a1, 16, 64); a1 += __shfl_xor(a1, 32, 64);
    a2 += __shfl_xor(a2, 16, 64); a2 += __shfl_xor(a2, 32, 64);
    a3 += __shfl_xor(a3, 16, 64); a3 += __shfl_xor(a3, 32, 64);
    a4 += __shfl_xor(a4, 16, 64); a4 += __shfl_xor(a4, 32, 64);
    a5 += __shfl_xor(a5, 16, 64); a5 += __shfl_xor(a5, 32, 64);
    a6 += __shfl_xor(a6, 16, 64); a6 += __shfl_xor(a6, 32, 64);
    a7 += __shfl_xor(a7, 16, 64); a7 += __shfl_xor(a7, 32, 64);
    if (sub == 0) {
        float4 o0 = make_float4(a0, a1, a2, a3);
        float4 o1 = make_float4(a4, a5, a6, a7);
        *(float4*)(aggr + (size_t)n * 128 + c0)     = o0;
        *(float4*)(aggr + (size_t)n * 128 + c0 + 4) = o1;
    }
}

// ---------------------------------------------------------------- launch
extern "C" void kernel_launch(void* const* d_in, const int* in_sizes, int n_in,
                              void* d_out, int out_size, void* d_ws, size_t ws_size,
                              hipStream_t stream)
{
    const float* x    = (const float*)d_in[0];
    const int*   ei   = (const int*)d_in[1];
    const float* nt   = (const float*)d_in[2];
    const float* et   = (const float*)d_in[3];
    const float* mW1  = (const float*)d_in[4];
    const float* mb1  = (const float*)d_in[5];
    const float* m_g  = (const float*)d_in[6];
    const float* m_b  = (const float*)d_in[7];
    const float* m_m  = (const float*)d_in[8];
    const float* m_v  = (const float*)d_in[9];
    const float* mW2  = (const float*)d_in[10];
    const float* mb2  = (const float*)d_in[11];
    const float* resW = (const float*)d_in[12];
    const float* qW   = (const float*)d_in[13];
    const float* qb   = (const float*)d_in[14];
    const float* kW   = (const float*)d_in[15];
    const float* kb   = (const float*)d_in[16];
    const float* vW   = (const float*)d_in[17];
    const float* vb   = (const float*)d_in[18];
    const float* oW1  = (const float*)d_in[19];
    const float* ob1  = (const float*)d_in[20];
    const float* o_g  = (const float*)d_in[21];
    const float* o_b  = (const float*)d_in[22];
    const float* o_m  = (const float*)d_in[23];
    const float* o_v  = (const float*)d_in[24];
    const float* oW2  = (const float*)d_in[25];
    const float* ob2  = (const float*)d_in[26];
    float* out = (float*)d_out;

    const int N = in_sizes[0] / 128;
    const int E = in_sizes[1] / 2;

    // workspace layout (floats): eaq|eak | Q | K | V | exp | ssum | [ints] deg,row_start,cursor,part,esrc
    float* ws   = (float*)d_ws;
    float* eaq  = ws;
    float* eak  = ws + 128;
    float* Q    = ws + 256;
    float* K    = Q + (size_t)N * 128;
    float* V    = K + (size_t)N * 128;
    float* exp_ = V + (size_t)N * 128;
    float* ssum = exp_ + (size_t)E * 8;
    int* deg       = (int*)(ssum + (size_t)N * 8);
    int* row_start = deg + N;
    int* cursor    = row_start + N;
    int* part      = cursor + N;
    int* esrc      = part + 256;
    float* aggr = Q;              // Q dead after edge pass 1 (Q16 uses half the region)
    ushort* Q16 = (ushort*)Q;     // Q in bf16
    ushort* V16 = (ushort*)V;     // V in bf16
    // bf16 weight planes live in dead regions:
    //   qkv planes in ssum (consumed by k_mm_qkv BEFORE ssum memset)
    //   out planes in exp_ (written AFTER k_aggr, when exp_ is dead)
    ushort* Pq = (ushort*)ssum;   // 3 * 32768 ushorts = 192 KB  (<< N*8 floats)
    ushort* Po = (ushort*)exp_;   // 192 KB  (<< E*8 floats)

    const int nbm  = (N + BM - 1) / BM;
    const int nbo  = (N + 127) / 128;
    const int nbsc = (N + SCAN_CHUNK - 1) / SCAN_CHUNK;   // scan blocks (<=256)

    // --- weight prep + ea (before memsets; Pq aliases ssum) ---
    k_prep3<<<dim3(128, 3), 128, 0, stream>>>(qW, kW, vW, Pq);
    k_ea<<<1, 128, 0, stream>>>(nt, et, mW1, mb1, m_g, m_b, m_m, m_v, mW2, mb2,
                                qW, qb, kW, kb, eaq, eak);
    k_mm_qkv<<<dim3(nbm, 3), 1024, 0, stream>>>(x, Pq, eaq, eak, vb, Q16, K, V16, N);

    // planes consumed -> now zero ssum/deg (stream-ordered)
    hipMemsetAsync(ssum, 0, (size_t)N * 8 * sizeof(float), stream);
    hipMemsetAsync(deg, 0, (size_t)N * sizeof(int), stream);

    // CSR build (independent of Q/K/V values)
    k_hist<<<(E + 255) / 256, 256, 0, stream>>>(ei, deg, E);
    k_scan_partial<<<nbsc, 256, 0, stream>>>(deg, part, N);
    k_scan_top<<<1, 256, 0, stream>>>(part, nbsc);
    k_scan_final<<<nbsc, 256, 0, stream>>>(deg, part, row_start, cursor, N);
    k_scatter<<<(E + 255) / 256, 256, 0, stream>>>(ei, cursor, esrc, E);

    // edge pass 1 in CSR order: K resident per node, bf16 Q gather, streaming exp writes
    k_edge1csr<<<(N + 3) / 4, 256, 0, stream>>>(esrc, row_start, deg, Q16, K, exp_, ssum, N);
    k_rsum<<<(N * 8 + 255) / 256, 256, 0, stream>>>(ssum, N * 8);
    k_aggr<<<(N + 3) / 4, 256, 0, stream>>>(esrc, row_start, deg, V16, exp_, ssum, aggr, N);

    // --- fused output chain via MFMA (exp_ dead now; Po aliases it) ---
    k_prep_out<<<dim3(128, 3), 128, 0, stream>>>(resW, oW1, oW2, Po);
    k_out4<<<nbo, 512, 0, stream>>>(x, Po, aggr, ob1, o_m, o_v, o_g, o_b, ob2, out, N);
}